// Round 4
// baseline (1538.222 us; speedup 1.0000x reference)
//
#include <hip/hip_runtime.h>
#include <hip/hip_bf16.h>

#define SEQ   2048
#define Dm    256
#define NE    1024
#define TT    16384   // B*S = 8*2048
#define TAU   0.05f   // near-tie gap threshold for f64 re-rank

// ---------------------------------------------------------------- transpose
// embeds[n][d][e] (f32) -> embT[n][e][d] (f32, ws)
__global__ void k_transpose(const float* __restrict__ emb, float* __restrict__ embT){
    __shared__ float tile[32][33];
    const int n  = blockIdx.z;
    const int e0 = blockIdx.x << 5, d0 = blockIdx.y << 5;
    const int tx = threadIdx.x, ty = threadIdx.y;
    const float* src = emb + (size_t)n * Dm * NE;
    float* dst = embT + (size_t)n * NE * Dm;
    #pragma unroll
    for (int i = ty; i < 32; i += 8)
        tile[i][tx] = src[(size_t)(d0 + i) * NE + e0 + tx];
    __syncthreads();
    #pragma unroll
    for (int i = ty; i < 32; i += 8)
        dst[(size_t)(e0 + i) * Dm + d0 + tx] = tile[tx][i];
}

// ---------------------------------------------------------------- e2 norms (+ zero flag counter)
__global__ void k_e2(const float* __restrict__ emb, float* __restrict__ e2,
                     int* __restrict__ cnt){
    if (blockIdx.x == 0 && blockIdx.y == 0 && threadIdx.x == 0) *cnt = 0;
    const int n = blockIdx.y;
    const int e = (blockIdx.x << 8) + threadIdx.x;
    const float* p = emb + (size_t)n * Dm * NE + e;
    float s = 0.f;
    #pragma unroll 8
    for (int d = 0; d < Dm; ++d){ float v = p[(size_t)d * NE]; s = fmaf(v, v, s); }
    e2[n * NE + e] = s;
}

// ---------------------------------------------------------------- conv (f32)
__global__ __launch_bounds__(256) void k_conv(
    const float* __restrict__ x,
    const float* __restrict__ w0, const float* __restrict__ w1,
    const float* __restrict__ w2, const float* __restrict__ w3,
    const float* __restrict__ b0, const float* __restrict__ b1,
    const float* __restrict__ b2, const float* __restrict__ b3,
    float* __restrict__ ic)
{
    __shared__ float xs[10][512];   // rows s0-3 .. s0+6, col c = 127 + m (zero padded)
    const int tid = threadIdx.x;
    const int t0 = blockIdx.x << 2;
    const int bb = t0 >> 11, s0 = t0 & (SEQ - 1);
    for (int idx = tid; idx < 10 * 512; idx += 256){
        const int r = idx >> 9, c = idx & 511;
        const int m = c - 127, s = s0 - 3 + r;
        float v = 0.f;
        if ((unsigned)m < (unsigned)Dm && (unsigned)s < (unsigned)SEQ)
            v = x[(size_t)((bb << 11) + s) * Dm + m];
        xs[r][c] = v;
    }
    __syncthreads();

    const int srl = tid >> 6, lane = tid & 63, d0 = lane << 2;
    const int t = t0 + srl;
    float acc[4][4] = {};
    float cur[7][4], nxt[7][4];
    #pragma unroll
    for (int r = 0; r < 7; ++r){
        const float4 v = *reinterpret_cast<const float4*>(&xs[srl + r][d0]);
        cur[r][0] = v.x; cur[r][1] = v.y; cur[r][2] = v.z; cur[r][3] = v.w;
    }
    const float* wrow[16] = { w0,
        w1, w1 + Dm, w1 + 2*Dm,
        w2, w2 + Dm, w2 + 2*Dm, w2 + 3*Dm, w2 + 4*Dm,
        w3, w3 + Dm, w3 + 2*Dm, w3 + 3*Dm, w3 + 4*Dm, w3 + 5*Dm, w3 + 6*Dm };
    const int rowN[16]  = {0, 1,1,1, 2,2,2,2,2, 3,3,3,3,3,3,3};
    const int rowRR[16] = {3, 2,3,4, 1,2,3,4,5, 0,1,2,3,4,5,6};

    for (int g = 0; g < 64; ++g){
        #pragma unroll
        for (int r = 0; r < 7; ++r){
            const float4 v = *reinterpret_cast<const float4*>(&xs[srl + r][d0 + (g << 2) + 4]);
            nxt[r][0] = v.x; nxt[r][1] = v.y; nxt[r][2] = v.z; nxt[r][3] = v.w;
        }
        #pragma unroll
        for (int row = 0; row < 16; ++row){
            const float* wr = wrow[row];                 // wave-uniform -> s_load
            const int rr = rowRR[row], n = rowN[row];
            const float wv0 = wr[(g << 2) + 0];
            const float wv1 = wr[(g << 2) + 1];
            const float wv2 = wr[(g << 2) + 2];
            const float wv3 = wr[(g << 2) + 3];
            #pragma unroll
            for (int dd = 0; dd < 4; ++dd){
                const float xq0 = cur[rr][dd];
                const float xq1 = (dd + 1 < 4) ? cur[rr][dd + 1] : nxt[rr][dd - 3];
                const float xq2 = (dd + 2 < 4) ? cur[rr][dd + 2] : nxt[rr][dd - 2];
                const float xq3 = (dd + 3 < 4) ? cur[rr][dd + 3] : nxt[rr][dd - 1];
                acc[n][dd] = fmaf(xq0, wv0, acc[n][dd]);
                acc[n][dd] = fmaf(xq1, wv1, acc[n][dd]);
                acc[n][dd] = fmaf(xq2, wv2, acc[n][dd]);
                acc[n][dd] = fmaf(xq3, wv3, acc[n][dd]);
            }
        }
        #pragma unroll
        for (int r = 0; r < 7; ++r){
            cur[r][0] = nxt[r][0]; cur[r][1] = nxt[r][1];
            cur[r][2] = nxt[r][2]; cur[r][3] = nxt[r][3];
        }
    }

    const float bias[4] = { b0[0], b1[0], b2[0], b3[0] };
    #pragma unroll
    for (int n = 0; n < 4; ++n){
        const float o0 = fmaxf(acc[n][0] + bias[n], 0.f);
        const float o1 = fmaxf(acc[n][1] + bias[n], 0.f);
        const float o2 = fmaxf(acc[n][2] + bias[n], 0.f);
        const float o3 = fmaxf(acc[n][3] + bias[n], 0.f);
        *reinterpret_cast<float4*>(&ic[(size_t)t * 1024 + n * Dm + d0]) =
            make_float4(o0, o1, o2, o3);
    }
}

// ---------------------------------------------------------------- VQ argmin (f32 + near-tie flagging)
__global__ __launch_bounds__(256) void k_vq(
    const float* __restrict__ ic, const float* __restrict__ embT,
    const float* __restrict__ e2g, int* __restrict__ idx_ws, float* __restrict__ am,
    int* __restrict__ cnt, int2* __restrict__ flags)
{
    __shared__ float As[64][257];
    __shared__ float Bs[64][257];
    __shared__ float e2s[NE];
    const int tid = threadIdx.x;
    const int n  = blockIdx.y;
    const int t0 = blockIdx.x << 6;

    for (int idx = tid; idx < 64 * 64; idx += 256){
        const int row = idx >> 6, c4 = (idx & 63) << 2;
        const float4 v = *reinterpret_cast<const float4*>(
            &ic[(size_t)(t0 + row) * 1024 + n * Dm + c4]);
        As[row][c4] = v.x; As[row][c4 + 1] = v.y; As[row][c4 + 2] = v.z; As[row][c4 + 3] = v.w;
    }
    for (int idx = tid; idx < NE; idx += 256) e2s[idx] = e2g[n * NE + idx];

    const int ty = tid >> 4, tx = tid & 15;
    float mn[4]  = {3.4e38f, 3.4e38f, 3.4e38f, 3.4e38f};
    float mn2[4] = {3.4e38f, 3.4e38f, 3.4e38f, 3.4e38f};
    int   mi[4]  = {0, 0, 0, 0};

    for (int e0 = 0; e0 < NE; e0 += 64){
        __syncthreads();
        for (int idx = tid; idx < 64 * 64; idx += 256){
            const int er = idx >> 6, c4 = (idx & 63) << 2;
            const float4 v = *reinterpret_cast<const float4*>(
                &embT[((size_t)n * NE + e0 + er) * Dm + c4]);
            Bs[er][c4] = v.x; Bs[er][c4 + 1] = v.y; Bs[er][c4 + 2] = v.z; Bs[er][c4 + 3] = v.w;
        }
        __syncthreads();

        float dot[4][4] = {};
        #pragma unroll 4
        for (int k = 0; k < Dm; ++k){
            const float a0 = As[(ty << 2) + 0][k];
            const float a1 = As[(ty << 2) + 1][k];
            const float a2 = As[(ty << 2) + 2][k];
            const float a3 = As[(ty << 2) + 3][k];
            const float q0 = Bs[(tx << 2) + 0][k];
            const float q1 = Bs[(tx << 2) + 1][k];
            const float q2 = Bs[(tx << 2) + 2][k];
            const float q3 = Bs[(tx << 2) + 3][k];
            dot[0][0] = fmaf(a0, q0, dot[0][0]); dot[0][1] = fmaf(a0, q1, dot[0][1]);
            dot[0][2] = fmaf(a0, q2, dot[0][2]); dot[0][3] = fmaf(a0, q3, dot[0][3]);
            dot[1][0] = fmaf(a1, q0, dot[1][0]); dot[1][1] = fmaf(a1, q1, dot[1][1]);
            dot[1][2] = fmaf(a1, q2, dot[1][2]); dot[1][3] = fmaf(a1, q3, dot[1][3]);
            dot[2][0] = fmaf(a2, q0, dot[2][0]); dot[2][1] = fmaf(a2, q1, dot[2][1]);
            dot[2][2] = fmaf(a2, q2, dot[2][2]); dot[2][3] = fmaf(a2, q3, dot[2][3]);
            dot[3][0] = fmaf(a3, q0, dot[3][0]); dot[3][1] = fmaf(a3, q1, dot[3][1]);
            dot[3][2] = fmaf(a3, q2, dot[3][2]); dot[3][3] = fmaf(a3, q3, dot[3][3]);
        }
        #pragma unroll
        for (int l = 0; l < 4; ++l){
            const int e = e0 + (tx << 2) + l;
            const float ee = e2s[e];
            #pragma unroll
            for (int j = 0; j < 4; ++j){
                const float v = fmaf(-2.f, dot[j][l], ee);
                if (v < mn[j]){ mn2[j] = mn[j]; mn[j] = v; mi[j] = e; }
                else if (v < mn2[j]){ mn2[j] = v; }
            }
        }
    }

    #pragma unroll
    for (int s = 1; s < 16; s <<= 1){
        #pragma unroll
        for (int j = 0; j < 4; ++j){
            const float om  = __shfl_xor(mn[j],  s, 64);
            const float om2 = __shfl_xor(mn2[j], s, 64);
            const int   oi  = __shfl_xor(mi[j],  s, 64);
            if (om < mn[j] || (om == mn[j] && oi < mi[j])){
                mn2[j] = fminf(mn[j], om2);
                mn[j] = om; mi[j] = oi;
            } else {
                mn2[j] = fminf(mn2[j], om);
            }
        }
    }
    if (tx == 0){
        #pragma unroll
        for (int j = 0; j < 4; ++j){
            const int t = t0 + (ty << 2) + j;
            idx_ws[t * 4 + n] = mi[j];
            am[(size_t)t * 4 + n] = (float)mi[j];
            if (mn2[j] - mn[j] < TAU){
                const int pos = atomicAdd(cnt, 1);
                flags[pos] = make_int2(t, n);
            }
        }
    }
}

// ---------------------------------------------------------------- f64 re-rank of flagged rows
__global__ __launch_bounds__(256) void k_fix(
    const float* __restrict__ x,
    const float* __restrict__ w0, const float* __restrict__ w1,
    const float* __restrict__ w2, const float* __restrict__ w3,
    const float* __restrict__ b0, const float* __restrict__ b1,
    const float* __restrict__ b2, const float* __restrict__ b3,
    const float* __restrict__ embT,
    const int* __restrict__ cnt, const int2* __restrict__ flags,
    int* __restrict__ idx_ws, float* __restrict__ am)
{
    __shared__ double fl[Dm];
    __shared__ double rD[4];
    __shared__ int    rE[4];
    const int tid = threadIdx.x;
    const int total = *cnt;
    const float* wP[4] = { w0, w1, w2, w3 };
    const float* bP[4] = { b0, b1, b2, b3 };
    const int   kN[4] = { 1, 3, 5, 7 };

    for (int item = blockIdx.x; item < total; item += gridDim.x){
        const int2 f = flags[item];
        const int t = f.x, n = f.y;
        const int bb = t >> 11, s = t & (SEQ - 1);
        const int k = kN[n], pad = (k - 1) >> 1;
        // ---- f64 conv for this row, d = tid
        {
            const int d = tid;
            double acc = (double)bP[n][0];
            for (int dh = 0; dh < k; ++dh){
                const int sr = s - pad + dh;
                if ((unsigned)sr < (unsigned)SEQ){
                    const float* xr = x + (size_t)((bb << 11) + sr) * Dm;
                    const float* wr = wP[n] + dh * Dm;
                    const int lo = (d - 127 < 0) ? 0 : d - 127;        // m = input dim index
                    const int hi = (d + 129 > Dm) ? Dm : d + 129;      // j = m-d+127 in [0,255]
                    for (int m = lo; m < hi; ++m)
                        acc += (double)xr[m] * (double)wr[m - d + 127];
                }
            }
            fl[d] = (acc > 0.0) ? acc : 0.0;
        }
        __syncthreads();
        // ---- f64 distances over all 1024 embeddings (4 per thread)
        double bD = 1e300; int bE = 0;
        #pragma unroll
        for (int ee = 0; ee < 4; ++ee){
            const int e = (ee << 8) + tid;
            const float* ep = embT + ((size_t)n * NE + e) * Dm;
            double dot = 0.0, e2 = 0.0;
            for (int d = 0; d < Dm; ++d){
                const double v = (double)ep[d];
                dot += v * fl[d];
                e2  += v * v;
            }
            const double dist = e2 - 2.0 * dot;
            if (dist < bD || (dist == bD && e < bE)){ bD = dist; bE = e; }
        }
        #pragma unroll
        for (int sft = 1; sft < 64; sft <<= 1){
            const double od = __shfl_xor(bD, sft, 64);
            const int    oe = __shfl_xor(bE, sft, 64);
            if (od < bD || (od == bD && oe < bE)){ bD = od; bE = oe; }
        }
        if ((tid & 63) == 0){ rD[tid >> 6] = bD; rE[tid >> 6] = bE; }
        __syncthreads();
        if (tid == 0){
            #pragma unroll
            for (int wv = 1; wv < 4; ++wv)
                if (rD[wv] < rD[0] || (rD[wv] == rD[0] && rE[wv] < rE[0])){
                    rD[0] = rD[wv]; rE[0] = rE[wv];
                }
            idx_ws[t * 4 + n] = rE[0];
            am[(size_t)t * 4 + n] = (float)rE[0];
        }
        __syncthreads();
    }
}

// ---------------------------------------------------------------- gather + gate + z_q
__global__ __launch_bounds__(256) void k_final(
    const int* __restrict__ idx_ws, const float* __restrict__ embT,
    const float* __restrict__ gw, const float* __restrict__ gb,
    float* __restrict__ qc, float* __restrict__ zq)
{
    __shared__ float gws[4][Dm];
    const int tid = threadIdx.x;
    for (int i = tid; i < 4 * Dm; i += 256) gws[i >> 8][i & 255] = gw[i];
    __syncthreads();
    const int t = (blockIdx.x << 2) + (tid >> 6);
    const int lane = tid & 63, d0 = lane << 2;

    float q[4][4];
    #pragma unroll
    for (int n = 0; n < 4; ++n){
        const int e = idx_ws[t * 4 + n];
        const float4 v = *reinterpret_cast<const float4*>(
            &embT[((size_t)n * NE + e) * Dm + d0]);
        q[n][0] = v.x; q[n][1] = v.y; q[n][2] = v.z; q[n][3] = v.w;
        *reinterpret_cast<float4*>(&qc[(size_t)t * 1024 + n * Dm + d0]) = v;
    }
    float part[4];
    #pragma unroll
    for (int n = 0; n < 4; ++n){
        part[n] = q[0][0] * gws[n][d0]     + q[0][1] * gws[n][d0 + 1]
                + q[0][2] * gws[n][d0 + 2] + q[0][3] * gws[n][d0 + 3];
    }
    #pragma unroll
    for (int s = 1; s < 64; s <<= 1){
        #pragma unroll
        for (int n = 0; n < 4; ++n) part[n] += __shfl_xor(part[n], s, 64);
    }
    float lg[4];
    #pragma unroll
    for (int n = 0; n < 4; ++n) lg[n] = part[n] + gb[n];
    const float mx = fmaxf(fmaxf(lg[0], lg[1]), fmaxf(lg[2], lg[3]));
    float ex[4], ssum = 0.f;
    #pragma unroll
    for (int n = 0; n < 4; ++n){ ex[n] = expf(lg[n] - mx); ssum += ex[n]; }
    const float inv = 1.f / ssum;
    float z[4];
    #pragma unroll
    for (int dd = 0; dd < 4; ++dd)
        z[dd] = (ex[0] * q[0][dd] + ex[1] * q[1][dd] + ex[2] * q[2][dd] + ex[3] * q[3][dd]) * inv;
    *reinterpret_cast<float4*>(&zq[(size_t)t * Dm + d0]) =
        make_float4(z[0], z[1], z[2], z[3]);
}

// ---------------------------------------------------------------- launch
extern "C" void kernel_launch(void* const* d_in, const int* in_sizes, int n_in,
                              void* d_out, int out_size, void* d_ws, size_t ws_size,
                              hipStream_t stream)
{
    const float* x   = (const float*)d_in[0];
    const float* w0  = (const float*)d_in[1];
    const float* b0  = (const float*)d_in[2];
    const float* w1  = (const float*)d_in[3];
    const float* b1  = (const float*)d_in[4];
    const float* w2  = (const float*)d_in[5];
    const float* b2  = (const float*)d_in[6];
    const float* w3  = (const float*)d_in[7];
    const float* b3  = (const float*)d_in[8];
    const float* emb = (const float*)d_in[9];
    const float* gw  = (const float*)d_in[10];
    const float* gb  = (const float*)d_in[11];

    float* out = (float*)d_out;
    float* zq = out;                    //  4,194,304  (T x 256)
    float* am = out + 4194304;          //     65,536  (T x 4)
    float* ic = out + 4259840;          // 16,777,216  (T x 1024)
    float* qc = out + 21037056;         // 16,777,216  (T x 1024)

    float* ws    = (float*)d_ws;
    float* embT  = ws;                          // [4][1024][256] f32
    float* e2    = ws + 1048576;                // [4][1024]      f32
    int*   idxs  = (int*)(ws + 1052672);        // [16384][4]     i32
    int*   cnt   = (int*)(ws + 1118208);        // 1 i32
    int2*  flags = (int2*)(ws + 1118212);       // up to 262144 int2

    hipLaunchKernelGGL(k_transpose, dim3(32, 8, 4), dim3(32, 8), 0, stream, emb, embT);
    hipLaunchKernelGGL(k_e2,        dim3(4, 4),     dim3(256),   0, stream, emb, e2, cnt);
    hipLaunchKernelGGL(k_conv,      dim3(4096),     dim3(256),   0, stream,
                       x, w0, w1, w2, w3, b0, b1, b2, b3, ic);
    hipLaunchKernelGGL(k_vq,        dim3(256, 4),   dim3(256),   0, stream,
                       ic, embT, e2, idxs, am, cnt, flags);
    hipLaunchKernelGGL(k_fix,       dim3(512),      dim3(256),   0, stream,
                       x, w0, w1, w2, w3, b0, b1, b2, b3, embT, cnt, flags, idxs, am);
    hipLaunchKernelGGL(k_final,     dim3(4096),     dim3(256),   0, stream,
                       idxs, embT, gw, gb, qc, zq);
}

// Round 5
// 957.159 us; speedup vs baseline: 1.6071x; 1.6071x over previous
//
#include <hip/hip_runtime.h>
#include <hip/hip_bf16.h>

#define SEQ   2048
#define Dm    256
#define NE    1024
#define TT    16384   // B*S = 8*2048
#define TAU   0.05f   // near-tie gap threshold for f64 re-rank
#define FLAGCAP 131072

typedef __attribute__((ext_vector_type(8))) short          bf16x8;
typedef __attribute__((ext_vector_type(4))) float          f32x4;
typedef __attribute__((ext_vector_type(8))) unsigned short us8;

__device__ __forceinline__ void bfsplit(float x, unsigned short& h, unsigned short& l){
    __hip_bfloat16 bh = __float2bfloat16(x);
    h = *reinterpret_cast<unsigned short*>(&bh);
    union { unsigned u; float f; } c; c.u = (unsigned)h << 16;
    __hip_bfloat16 bl = __float2bfloat16(x - c.f);
    l = *reinterpret_cast<unsigned short*>(&bl);
}

// ---------------------------------------------------------------- transpose
// embeds[n][d][e] (f32) -> embT[n][e][d] (f32, ws)
__global__ void k_transpose(const float* __restrict__ emb, float* __restrict__ embT){
    __shared__ float tile[32][33];
    const int n  = blockIdx.z;
    const int e0 = blockIdx.x << 5, d0 = blockIdx.y << 5;
    const int tx = threadIdx.x, ty = threadIdx.y;
    const float* src = emb + (size_t)n * Dm * NE;
    float* dst = embT + (size_t)n * NE * Dm;
    #pragma unroll
    for (int i = ty; i < 32; i += 8)
        tile[i][tx] = src[(size_t)(d0 + i) * NE + e0 + tx];
    __syncthreads();
    #pragma unroll
    for (int i = ty; i < 32; i += 8)
        dst[(size_t)(e0 + i) * Dm + d0 + tx] = tile[tx][i];
}

// ---------------------------------------------------------------- e2 norms (+ zero flag counter)
__global__ void k_e2(const float* __restrict__ emb, float* __restrict__ e2,
                     int* __restrict__ cnt){
    if (blockIdx.x == 0 && blockIdx.y == 0 && threadIdx.x == 0) *cnt = 0;
    const int n = blockIdx.y;
    const int e = (blockIdx.x << 8) + threadIdx.x;
    const float* p = emb + (size_t)n * Dm * NE + e;
    float s = 0.f;
    #pragma unroll 8
    for (int d = 0; d < Dm; ++d){ float v = p[(size_t)d * NE]; s = fmaf(v, v, s); }
    e2[n * NE + e] = s;
}

// ---------------------------------------------------------------- split embT into bf16 hi/lo
__global__ __launch_bounds__(256) void k_cvt(const float* __restrict__ embT,
                                             unsigned short* __restrict__ eh,
                                             unsigned short* __restrict__ el){
    const int i = ((blockIdx.x << 8) + threadIdx.x) << 2;   // 4 f32 per thread
    const float4 v = *reinterpret_cast<const float4*>(&embT[i]);
    ushort4 h, l;
    bfsplit(v.x, h.x, l.x); bfsplit(v.y, h.y, l.y);
    bfsplit(v.z, h.z, l.z); bfsplit(v.w, h.w, l.w);
    *reinterpret_cast<ushort4*>(&eh[i]) = h;
    *reinterpret_cast<ushort4*>(&el[i]) = l;
}

// ---------------------------------------------------------------- conv (f32)
__global__ __launch_bounds__(256) void k_conv(
    const float* __restrict__ x,
    const float* __restrict__ w0, const float* __restrict__ w1,
    const float* __restrict__ w2, const float* __restrict__ w3,
    const float* __restrict__ b0, const float* __restrict__ b1,
    const float* __restrict__ b2, const float* __restrict__ b3,
    float* __restrict__ ic)
{
    __shared__ float xs[10][512];   // rows s0-3 .. s0+6, col c = 127 + m (zero padded)
    const int tid = threadIdx.x;
    const int t0 = blockIdx.x << 2;
    const int bb = t0 >> 11, s0 = t0 & (SEQ - 1);
    for (int idx = tid; idx < 10 * 512; idx += 256){
        const int r = idx >> 9, c = idx & 511;
        const int m = c - 127, s = s0 - 3 + r;
        float v = 0.f;
        if ((unsigned)m < (unsigned)Dm && (unsigned)s < (unsigned)SEQ)
            v = x[(size_t)((bb << 11) + s) * Dm + m];
        xs[r][c] = v;
    }
    __syncthreads();

    const int srl = tid >> 6, lane = tid & 63, d0 = lane << 2;
    const int t = t0 + srl;
    float acc[4][4] = {};
    float cur[7][4], nxt[7][4];
    #pragma unroll
    for (int r = 0; r < 7; ++r){
        const float4 v = *reinterpret_cast<const float4*>(&xs[srl + r][d0]);
        cur[r][0] = v.x; cur[r][1] = v.y; cur[r][2] = v.z; cur[r][3] = v.w;
    }
    const float* wrow[16] = { w0,
        w1, w1 + Dm, w1 + 2*Dm,
        w2, w2 + Dm, w2 + 2*Dm, w2 + 3*Dm, w2 + 4*Dm,
        w3, w3 + Dm, w3 + 2*Dm, w3 + 3*Dm, w3 + 4*Dm, w3 + 5*Dm, w3 + 6*Dm };
    const int rowN[16]  = {0, 1,1,1, 2,2,2,2,2, 3,3,3,3,3,3,3};
    const int rowRR[16] = {3, 2,3,4, 1,2,3,4,5, 0,1,2,3,4,5,6};

    for (int g = 0; g < 64; ++g){
        #pragma unroll
        for (int r = 0; r < 7; ++r){
            const float4 v = *reinterpret_cast<const float4*>(&xs[srl + r][d0 + (g << 2) + 4]);
            nxt[r][0] = v.x; nxt[r][1] = v.y; nxt[r][2] = v.z; nxt[r][3] = v.w;
        }
        #pragma unroll
        for (int row = 0; row < 16; ++row){
            const float* wr = wrow[row];                 // wave-uniform -> s_load
            const int rr = rowRR[row], n = rowN[row];
            const float wv0 = wr[(g << 2) + 0];
            const float wv1 = wr[(g << 2) + 1];
            const float wv2 = wr[(g << 2) + 2];
            const float wv3 = wr[(g << 2) + 3];
            #pragma unroll
            for (int dd = 0; dd < 4; ++dd){
                const float xq0 = cur[rr][dd];
                const float xq1 = (dd + 1 < 4) ? cur[rr][dd + 1] : nxt[rr][dd - 3];
                const float xq2 = (dd + 2 < 4) ? cur[rr][dd + 2] : nxt[rr][dd - 2];
                const float xq3 = (dd + 3 < 4) ? cur[rr][dd + 3] : nxt[rr][dd - 1];
                acc[n][dd] = fmaf(xq0, wv0, acc[n][dd]);
                acc[n][dd] = fmaf(xq1, wv1, acc[n][dd]);
                acc[n][dd] = fmaf(xq2, wv2, acc[n][dd]);
                acc[n][dd] = fmaf(xq3, wv3, acc[n][dd]);
            }
        }
        #pragma unroll
        for (int r = 0; r < 7; ++r){
            cur[r][0] = nxt[r][0]; cur[r][1] = nxt[r][1];
            cur[r][2] = nxt[r][2]; cur[r][3] = nxt[r][3];
        }
    }

    const float bias[4] = { b0[0], b1[0], b2[0], b3[0] };
    #pragma unroll
    for (int n = 0; n < 4; ++n){
        const float o0 = fmaxf(acc[n][0] + bias[n], 0.f);
        const float o1 = fmaxf(acc[n][1] + bias[n], 0.f);
        const float o2 = fmaxf(acc[n][2] + bias[n], 0.f);
        const float o3 = fmaxf(acc[n][3] + bias[n], 0.f);
        *reinterpret_cast<float4*>(&ic[(size_t)t * 1024 + n * Dm + d0]) =
            make_float4(o0, o1, o2, o3);
    }
}

// ---------------------------------------------------------------- VQ argmin: split-bf16 MFMA GEMM
// Block: 64 t-rows (blockIdx.x), codebook n (blockIdx.y). e loops in 4 chunks of 256.
// Wave w covers e-cols [w*64, w*64+64): 16 C-tiles of 16x16, K=256 in 8 steps of 32.
// dot ~= ah*bh + ah*bl + al*bh  (split-bf16, err ~1e-3; near-ties fixed by k_fix f64 pass)
__global__ __launch_bounds__(256) void k_vq(
    const float* __restrict__ ic,
    const unsigned short* __restrict__ ebh, const unsigned short* __restrict__ ebl,
    const float* __restrict__ e2g, int* __restrict__ idx_ws, float* __restrict__ am,
    int* __restrict__ cnt, int2* __restrict__ flags)
{
    // stride 40 shorts (80 B): b128 frag reads hit each bank exactly 8x (uniform)
    __shared__ alignas(16) unsigned short Ah[64][40], Al[64][40];
    __shared__ alignas(16) unsigned short Bh[256][40], Bl[256][40];

    const int tid  = threadIdx.x;
    const int lane = tid & 63;
    const int wv   = tid >> 6;
    const int tx   = lane & 15, tg = lane >> 4;
    const int n    = blockIdx.y;
    const int t0   = blockIdx.x << 6;

    float mn[16], mn2[16]; int mi[16];
    #pragma unroll
    for (int s = 0; s < 16; ++s){ mn[s] = 3.4e38f; mn2[s] = 3.4e38f; mi[s] = 0; }

    for (int ec = 0; ec < 4; ++ec){
        f32x4 acc[4][4];
        #pragma unroll
        for (int rb = 0; rb < 4; ++rb)
            #pragma unroll
            for (int cb = 0; cb < 4; ++cb)
                acc[rb][cb] = f32x4{0.f, 0.f, 0.f, 0.f};

        for (int ks = 0; ks < 8; ++ks){
            __syncthreads();
            // ---- stage A: 64 rows x 32 k (f32 -> bf16 hi/lo)
            #pragma unroll
            for (int i = 0; i < 2; ++i){
                const int f = tid + (i << 8);
                const int row = f >> 3, kq = (f & 7) << 2;
                const float4 v = *reinterpret_cast<const float4*>(
                    &ic[(size_t)(t0 + row) * 1024 + n * Dm + (ks << 5) + kq]);
                ushort4 h, l;
                bfsplit(v.x, h.x, l.x); bfsplit(v.y, h.y, l.y);
                bfsplit(v.z, h.z, l.z); bfsplit(v.w, h.w, l.w);
                *reinterpret_cast<ushort4*>(&Ah[row][kq]) = h;
                *reinterpret_cast<ushort4*>(&Al[row][kq]) = l;
            }
            // ---- stage B: 256 e-rows x 32 k (pre-split bf16)
            #pragma unroll
            for (int i = 0; i < 4; ++i){
                const int f = tid + (i << 8);
                const int row = f >> 2, k8 = (f & 3) << 3;
                const size_t g = ((size_t)((n << 10) + (ec << 8) + row) << 8) + (ks << 5) + k8;
                *reinterpret_cast<us8*>(&Bh[row][k8]) = *reinterpret_cast<const us8*>(&ebh[g]);
                *reinterpret_cast<us8*>(&Bl[row][k8]) = *reinterpret_cast<const us8*>(&ebl[g]);
            }
            __syncthreads();
            // ---- fragments + MFMA
            bf16x8 ah[4], al[4], bh[4], bl[4];
            #pragma unroll
            for (int rb = 0; rb < 4; ++rb){
                ah[rb] = *reinterpret_cast<const bf16x8*>(&Ah[(rb << 4) + tx][tg << 3]);
                al[rb] = *reinterpret_cast<const bf16x8*>(&Al[(rb << 4) + tx][tg << 3]);
            }
            #pragma unroll
            for (int cb = 0; cb < 4; ++cb){
                bh[cb] = *reinterpret_cast<const bf16x8*>(&Bh[(wv << 6) + (cb << 4) + tx][tg << 3]);
                bl[cb] = *reinterpret_cast<const bf16x8*>(&Bl[(wv << 6) + (cb << 4) + tx][tg << 3]);
            }
            #pragma unroll
            for (int rb = 0; rb < 4; ++rb)
                #pragma unroll
                for (int cb = 0; cb < 4; ++cb){
                    acc[rb][cb] = __builtin_amdgcn_mfma_f32_16x16x32_bf16(ah[rb], bh[cb], acc[rb][cb], 0, 0, 0);
                    acc[rb][cb] = __builtin_amdgcn_mfma_f32_16x16x32_bf16(ah[rb], bl[cb], acc[rb][cb], 0, 0, 0);
                    acc[rb][cb] = __builtin_amdgcn_mfma_f32_16x16x32_bf16(al[rb], bh[cb], acc[rb][cb], 0, 0, 0);
                }
        }
        // ---- chunk epilogue: dist = e2 - 2*dot, update running min/2nd-min (e ascending)
        #pragma unroll
        for (int cb = 0; cb < 4; ++cb){
            const int e = (ec << 8) + (wv << 6) + (cb << 4) + tx;
            const float ee = e2g[(n << 10) + e];
            #pragma unroll
            for (int rb = 0; rb < 4; ++rb)
                #pragma unroll
                for (int r = 0; r < 4; ++r){
                    const float v = fmaf(-2.f, acc[rb][cb][r], ee);
                    const int s = (rb << 2) + r;
                    if (v < mn[s]){ mn2[s] = mn[s]; mn[s] = v; mi[s] = e; }
                    else if (v < mn2[s]){ mn2[s] = v; }
                }
        }
    }

    // ---- reduce across the 16 lanes of the col-group (tx)
    #pragma unroll
    for (int sft = 1; sft < 16; sft <<= 1){
        #pragma unroll
        for (int s = 0; s < 16; ++s){
            const float om  = __shfl_xor(mn[s],  sft, 64);
            const float om2 = __shfl_xor(mn2[s], sft, 64);
            const int   oi  = __shfl_xor(mi[s],  sft, 64);
            if (om < mn[s] || (om == mn[s] && oi < mi[s])){
                mn2[s] = fminf(mn[s], om2);
                mn[s] = om; mi[s] = oi;
            } else {
                mn2[s] = fminf(mn2[s], om);
            }
        }
    }
    // ---- cross-wave reduce via LDS (reuse Ah region, 3 KB)
    __syncthreads();
    float* redMn  = reinterpret_cast<float*>(&Ah[0][0]);
    float* redMn2 = redMn + 256;
    int*   redMi  = reinterpret_cast<int*>(redMn + 512);
    if (tx == 0){
        #pragma unroll
        for (int rb = 0; rb < 4; ++rb)
            #pragma unroll
            for (int r = 0; r < 4; ++r){
                const int row = (rb << 4) + (tg << 2) + r;
                const int s = (rb << 2) + r;
                redMn [(wv << 6) + row] = mn[s];
                redMn2[(wv << 6) + row] = mn2[s];
                redMi [(wv << 6) + row] = mi[s];
            }
    }
    __syncthreads();
    if (tid < 64){
        const int row = tid;
        float bmn = redMn[row], bmn2 = redMn2[row];
        int   bmi = redMi[row];
        #pragma unroll
        for (int w = 1; w < 4; ++w){
            const float om  = redMn [(w << 6) + row];
            const float om2 = redMn2[(w << 6) + row];
            const int   oi  = redMi [(w << 6) + row];
            if (om < bmn || (om == bmn && oi < bmi)){
                bmn2 = fminf(bmn, om2);
                bmn = om; bmi = oi;
            } else {
                bmn2 = fminf(bmn2, om);
            }
        }
        const int t = t0 + row;
        idx_ws[t * 4 + n] = bmi;
        am[(size_t)t * 4 + n] = (float)bmi;
        if (bmn2 - bmn < TAU){
            const int pos = atomicAdd(cnt, 1);
            if (pos < FLAGCAP) flags[pos] = make_int2(t, n);
        }
    }
}

// ---------------------------------------------------------------- f64 re-rank of flagged rows
__global__ __launch_bounds__(256) void k_fix(
    const float* __restrict__ x,
    const float* __restrict__ w0, const float* __restrict__ w1,
    const float* __restrict__ w2, const float* __restrict__ w3,
    const float* __restrict__ b0, const float* __restrict__ b1,
    const float* __restrict__ b2, const float* __restrict__ b3,
    const float* __restrict__ embT,
    const int* __restrict__ cnt, const int2* __restrict__ flags,
    int* __restrict__ idx_ws, float* __restrict__ am)
{
    __shared__ double fl[Dm];
    __shared__ double rD[4];
    __shared__ int    rE[4];
    const int tid = threadIdx.x;
    const int total = (*cnt < FLAGCAP) ? *cnt : FLAGCAP;
    const float* wP[4] = { w0, w1, w2, w3 };
    const float* bP[4] = { b0, b1, b2, b3 };
    const int   kN[4] = { 1, 3, 5, 7 };

    for (int item = blockIdx.x; item < total; item += gridDim.x){
        const int2 f = flags[item];
        const int t = f.x, n = f.y;
        const int bb = t >> 11, s = t & (SEQ - 1);
        const int k = kN[n], pad = (k - 1) >> 1;
        // ---- f64 conv for this row, d = tid
        {
            const int d = tid;
            double acc = (double)bP[n][0];
            for (int dh = 0; dh < k; ++dh){
                const int sr = s - pad + dh;
                if ((unsigned)sr < (unsigned)SEQ){
                    const float* xr = x + (size_t)((bb << 11) + sr) * Dm;
                    const float* wr = wP[n] + dh * Dm;
                    const int lo = (d - 127 < 0) ? 0 : d - 127;        // m = input dim index
                    const int hi = (d + 129 > Dm) ? Dm : d + 129;      // j = m-d+127 in [0,255]
                    for (int m = lo; m < hi; ++m)
                        acc += (double)xr[m] * (double)wr[m - d + 127];
                }
            }
            fl[d] = (acc > 0.0) ? acc : 0.0;
        }
        __syncthreads();
        // ---- f64 distances over all 1024 embeddings (4 per thread)
        double bD = 1e300; int bE = 0;
        #pragma unroll
        for (int ee = 0; ee < 4; ++ee){
            const int e = (ee << 8) + tid;
            const float* ep = embT + ((size_t)n * NE + e) * Dm;
            double dot = 0.0, e2 = 0.0;
            for (int d = 0; d < Dm; ++d){
                const double v = (double)ep[d];
                dot += v * fl[d];
                e2  += v * v;
            }
            const double dist = e2 - 2.0 * dot;
            if (dist < bD || (dist == bD && e < bE)){ bD = dist; bE = e; }
        }
        #pragma unroll
        for (int sft = 1; sft < 64; sft <<= 1){
            const double od = __shfl_xor(bD, sft, 64);
            const int    oe = __shfl_xor(bE, sft, 64);
            if (od < bD || (od == bD && oe < bE)){ bD = od; bE = oe; }
        }
        if ((tid & 63) == 0){ rD[tid >> 6] = bD; rE[tid >> 6] = bE; }
        __syncthreads();
        if (tid == 0){
            #pragma unroll
            for (int wv = 1; wv < 4; ++wv)
                if (rD[wv] < rD[0] || (rD[wv] == rD[0] && rE[wv] < rE[0])){
                    rD[0] = rD[wv]; rE[0] = rE[wv];
                }
            idx_ws[t * 4 + n] = rE[0];
            am[(size_t)t * 4 + n] = (float)rE[0];
        }
        __syncthreads();
    }
}

// ---------------------------------------------------------------- gather + gate + z_q
__global__ __launch_bounds__(256) void k_final(
    const int* __restrict__ idx_ws, const float* __restrict__ embT,
    const float* __restrict__ gw, const float* __restrict__ gb,
    float* __restrict__ qc, float* __restrict__ zq)
{
    __shared__ float gws[4][Dm];
    const int tid = threadIdx.x;
    for (int i = tid; i < 4 * Dm; i += 256) gws[i >> 8][i & 255] = gw[i];
    __syncthreads();
    const int t = (blockIdx.x << 2) + (tid >> 6);
    const int lane = tid & 63, d0 = lane << 2;

    float q[4][4];
    #pragma unroll
    for (int n = 0; n < 4; ++n){
        const int e = idx_ws[t * 4 + n];
        const float4 v = *reinterpret_cast<const float4*>(
            &embT[((size_t)n * NE + e) * Dm + d0]);
        q[n][0] = v.x; q[n][1] = v.y; q[n][2] = v.z; q[n][3] = v.w;
        *reinterpret_cast<float4*>(&qc[(size_t)t * 1024 + n * Dm + d0]) = v;
    }
    float part[4];
    #pragma unroll
    for (int n = 0; n < 4; ++n){
        part[n] = q[0][0] * gws[n][d0]     + q[0][1] * gws[n][d0 + 1]
                + q[0][2] * gws[n][d0 + 2] + q[0][3] * gws[n][d0 + 3];
    }
    #pragma unroll
    for (int s = 1; s < 64; s <<= 1){
        #pragma unroll
        for (int n = 0; n < 4; ++n) part[n] += __shfl_xor(part[n], s, 64);
    }
    float lg[4];
    #pragma unroll
    for (int n = 0; n < 4; ++n) lg[n] = part[n] + gb[n];
    const float mx = fmaxf(fmaxf(lg[0], lg[1]), fmaxf(lg[2], lg[3]));
    float ex[4], ssum = 0.f;
    #pragma unroll
    for (int n = 0; n < 4; ++n){ ex[n] = expf(lg[n] - mx); ssum += ex[n]; }
    const float inv = 1.f / ssum;
    float z[4];
    #pragma unroll
    for (int dd = 0; dd < 4; ++dd)
        z[dd] = (ex[0] * q[0][dd] + ex[1] * q[1][dd] + ex[2] * q[2][dd] + ex[3] * q[3][dd]) * inv;
    *reinterpret_cast<float4*>(&zq[(size_t)t * Dm + d0]) =
        make_float4(z[0], z[1], z[2], z[3]);
}

// ---------------------------------------------------------------- launch
extern "C" void kernel_launch(void* const* d_in, const int* in_sizes, int n_in,
                              void* d_out, int out_size, void* d_ws, size_t ws_size,
                              hipStream_t stream)
{
    const float* x   = (const float*)d_in[0];
    const float* w0  = (const float*)d_in[1];
    const float* b0  = (const float*)d_in[2];
    const float* w1  = (const float*)d_in[3];
    const float* b1  = (const float*)d_in[4];
    const float* w2  = (const float*)d_in[5];
    const float* b2  = (const float*)d_in[6];
    const float* w3  = (const float*)d_in[7];
    const float* b3  = (const float*)d_in[8];
    const float* emb = (const float*)d_in[9];
    const float* gw  = (const float*)d_in[10];
    const float* gb  = (const float*)d_in[11];

    float* out = (float*)d_out;
    float* zq = out;                    //  4,194,304  (T x 256)
    float* am = out + 4194304;          //     65,536  (T x 4)
    float* ic = out + 4259840;          // 16,777,216  (T x 1024)
    float* qc = out + 21037056;         // 16,777,216  (T x 1024)

    float* ws    = (float*)d_ws;
    float* embT  = ws;                                  // [4][1024][256] f32
    float* e2    = ws + 1048576;                        // [4][1024]      f32
    int*   idxs  = (int*)(ws + 1052672);                // [16384][4]     i32
    int*   cnt   = (int*)(ws + 1118208);                // 1 i32
    int2*  flags = (int2*)(ws + 1118212);               // FLAGCAP int2
    unsigned short* ebh = (unsigned short*)(ws + 1380360);  // [4][1024][256] bf16 hi
    unsigned short* ebl = (unsigned short*)(ws + 1904648);  // [4][1024][256] bf16 lo

    hipLaunchKernelGGL(k_transpose, dim3(32, 8, 4), dim3(32, 8), 0, stream, emb, embT);
    hipLaunchKernelGGL(k_e2,        dim3(4, 4),     dim3(256),   0, stream, emb, e2, cnt);
    hipLaunchKernelGGL(k_cvt,       dim3(1024),     dim3(256),   0, stream, embT, ebh, ebl);
    hipLaunchKernelGGL(k_conv,      dim3(4096),     dim3(256),   0, stream,
                       x, w0, w1, w2, w3, b0, b1, b2, b3, ic);
    hipLaunchKernelGGL(k_vq,        dim3(256, 4),   dim3(256),   0, stream,
                       ic, ebh, ebl, e2, idxs, am, cnt, flags);
    hipLaunchKernelGGL(k_fix,       dim3(512),      dim3(256),   0, stream,
                       x, w0, w1, w2, w3, b0, b1, b2, b3, embT, cnt, flags, idxs, am);
    hipLaunchKernelGGL(k_final,     dim3(4096),     dim3(256),   0, stream,
                       idxs, embT, gw, gb, qc, zq);
}

// Round 6
// 888.419 us; speedup vs baseline: 1.7314x; 1.0774x over previous
//
#include <hip/hip_runtime.h>
#include <hip/hip_bf16.h>

#define SEQ   2048
#define Dm    256
#define NE    1024
#define TT    16384   // B*S = 8*2048
#define TAU   0.05f   // near-tie gap threshold for f64 re-rank
#define FLAGCAP 131072

typedef __attribute__((ext_vector_type(8))) short          bf16x8;
typedef __attribute__((ext_vector_type(4))) float          f32x4;
typedef __attribute__((ext_vector_type(8))) unsigned short us8;

__device__ __forceinline__ void bfsplit(float x, unsigned short& h, unsigned short& l){
    __hip_bfloat16 bh = __float2bfloat16(x);
    h = *reinterpret_cast<unsigned short*>(&bh);
    union { unsigned u; float f; } c; c.u = (unsigned)h << 16;
    __hip_bfloat16 bl = __float2bfloat16(x - c.f);
    l = *reinterpret_cast<unsigned short*>(&bl);
}

// ---------------------------------------------------------------- transpose
// embeds[n][d][e] (f32) -> embT[n][e][d] (f32, ws)
__global__ void k_transpose(const float* __restrict__ emb, float* __restrict__ embT){
    __shared__ float tile[32][33];
    const int n  = blockIdx.z;
    const int e0 = blockIdx.x << 5, d0 = blockIdx.y << 5;
    const int tx = threadIdx.x, ty = threadIdx.y;
    const float* src = emb + (size_t)n * Dm * NE;
    float* dst = embT + (size_t)n * NE * Dm;
    #pragma unroll
    for (int i = ty; i < 32; i += 8)
        tile[i][tx] = src[(size_t)(d0 + i) * NE + e0 + tx];
    __syncthreads();
    #pragma unroll
    for (int i = ty; i < 32; i += 8)
        dst[(size_t)(e0 + i) * Dm + d0 + tx] = tile[tx][i];
}

// ---------------------------------------------------------------- e2 norms (+ zero flag counter)
__global__ void k_e2(const float* __restrict__ emb, float* __restrict__ e2,
                     int* __restrict__ cnt){
    if (blockIdx.x == 0 && blockIdx.y == 0 && threadIdx.x == 0) *cnt = 0;
    const int n = blockIdx.y;
    const int e = (blockIdx.x << 8) + threadIdx.x;
    const float* p = emb + (size_t)n * Dm * NE + e;
    float s = 0.f;
    #pragma unroll 8
    for (int d = 0; d < Dm; ++d){ float v = p[(size_t)d * NE]; s = fmaf(v, v, s); }
    e2[n * NE + e] = s;
}

// ---------------------------------------------------------------- split embT into bf16 hi/lo
__global__ __launch_bounds__(256) void k_cvt(const float* __restrict__ embT,
                                             unsigned short* __restrict__ eh,
                                             unsigned short* __restrict__ el){
    const int i = ((blockIdx.x << 8) + threadIdx.x) << 2;   // 4 f32 per thread
    const float4 v = *reinterpret_cast<const float4*>(&embT[i]);
    ushort4 h, l;
    bfsplit(v.x, h.x, l.x); bfsplit(v.y, h.y, l.y);
    bfsplit(v.z, h.z, l.z); bfsplit(v.w, h.w, l.w);
    *reinterpret_cast<ushort4*>(&eh[i]) = h;
    *reinterpret_cast<ushort4*>(&el[i]) = l;
}

// ---------------------------------------------------------------- conv (f32)
__global__ __launch_bounds__(256) void k_conv(
    const float* __restrict__ x,
    const float* __restrict__ w0, const float* __restrict__ w1,
    const float* __restrict__ w2, const float* __restrict__ w3,
    const float* __restrict__ b0, const float* __restrict__ b1,
    const float* __restrict__ b2, const float* __restrict__ b3,
    float* __restrict__ ic)
{
    __shared__ float xs[10][512];   // rows s0-3 .. s0+6, col c = 127 + m (zero padded)
    const int tid = threadIdx.x;
    const int t0 = blockIdx.x << 2;
    const int bb = t0 >> 11, s0 = t0 & (SEQ - 1);
    for (int idx = tid; idx < 10 * 512; idx += 256){
        const int r = idx >> 9, c = idx & 511;
        const int m = c - 127, s = s0 - 3 + r;
        float v = 0.f;
        if ((unsigned)m < (unsigned)Dm && (unsigned)s < (unsigned)SEQ)
            v = x[(size_t)((bb << 11) + s) * Dm + m];
        xs[r][c] = v;
    }
    __syncthreads();

    const int srl = tid >> 6, lane = tid & 63, d0 = lane << 2;
    const int t = t0 + srl;
    float acc[4][4] = {};
    float cur[7][4], nxt[7][4];
    #pragma unroll
    for (int r = 0; r < 7; ++r){
        const float4 v = *reinterpret_cast<const float4*>(&xs[srl + r][d0]);
        cur[r][0] = v.x; cur[r][1] = v.y; cur[r][2] = v.z; cur[r][3] = v.w;
    }
    const float* wrow[16] = { w0,
        w1, w1 + Dm, w1 + 2*Dm,
        w2, w2 + Dm, w2 + 2*Dm, w2 + 3*Dm, w2 + 4*Dm,
        w3, w3 + Dm, w3 + 2*Dm, w3 + 3*Dm, w3 + 4*Dm, w3 + 5*Dm, w3 + 6*Dm };
    const int rowN[16]  = {0, 1,1,1, 2,2,2,2,2, 3,3,3,3,3,3,3};
    const int rowRR[16] = {3, 2,3,4, 1,2,3,4,5, 0,1,2,3,4,5,6};

    for (int g = 0; g < 64; ++g){
        #pragma unroll
        for (int r = 0; r < 7; ++r){
            const float4 v = *reinterpret_cast<const float4*>(&xs[srl + r][d0 + (g << 2) + 4]);
            nxt[r][0] = v.x; nxt[r][1] = v.y; nxt[r][2] = v.z; nxt[r][3] = v.w;
        }
        #pragma unroll
        for (int row = 0; row < 16; ++row){
            const float* wr = wrow[row];                 // wave-uniform -> s_load
            const int rr = rowRR[row], n = rowN[row];
            const float wv0 = wr[(g << 2) + 0];
            const float wv1 = wr[(g << 2) + 1];
            const float wv2 = wr[(g << 2) + 2];
            const float wv3 = wr[(g << 2) + 3];
            #pragma unroll
            for (int dd = 0; dd < 4; ++dd){
                const float xq0 = cur[rr][dd];
                const float xq1 = (dd + 1 < 4) ? cur[rr][dd + 1] : nxt[rr][dd - 3];
                const float xq2 = (dd + 2 < 4) ? cur[rr][dd + 2] : nxt[rr][dd - 2];
                const float xq3 = (dd + 3 < 4) ? cur[rr][dd + 3] : nxt[rr][dd - 1];
                acc[n][dd] = fmaf(xq0, wv0, acc[n][dd]);
                acc[n][dd] = fmaf(xq1, wv1, acc[n][dd]);
                acc[n][dd] = fmaf(xq2, wv2, acc[n][dd]);
                acc[n][dd] = fmaf(xq3, wv3, acc[n][dd]);
            }
        }
        #pragma unroll
        for (int r = 0; r < 7; ++r){
            cur[r][0] = nxt[r][0]; cur[r][1] = nxt[r][1];
            cur[r][2] = nxt[r][2]; cur[r][3] = nxt[r][3];
        }
    }

    const float bias[4] = { b0[0], b1[0], b2[0], b3[0] };
    #pragma unroll
    for (int n = 0; n < 4; ++n){
        const float o0 = fmaxf(acc[n][0] + bias[n], 0.f);
        const float o1 = fmaxf(acc[n][1] + bias[n], 0.f);
        const float o2 = fmaxf(acc[n][2] + bias[n], 0.f);
        const float o3 = fmaxf(acc[n][3] + bias[n], 0.f);
        *reinterpret_cast<float4*>(&ic[(size_t)t * 1024 + n * Dm + d0]) =
            make_float4(o0, o1, o2, o3);
    }
}

// ---------------------------------------------------------------- VQ argmin v3
// Block: 64 t-rows, codebook n. A staged ONCE into LDS (bf16 hi/lo, padded rows).
// 4 waves, wave w owns e-strip [w*256, +256): B frags loaded global->reg (L2-hot),
// ZERO barriers in the main loop. dist = e2 - 2*(ah*bh + ah*bl + al*bh).
__global__ __launch_bounds__(256, 2) void k_vq(
    const float* __restrict__ ic,
    const unsigned short* __restrict__ ebh, const unsigned short* __restrict__ ebl,
    const float* __restrict__ e2g, int* __restrict__ idx_ws, float* __restrict__ am,
    int* __restrict__ cnt, int2* __restrict__ flags)
{
    // row stride 264 shorts (528 B): frag ds_read_b128 conflict-free per 8-lane phase
    __shared__ alignas(16) unsigned short Ahs[64][264];
    __shared__ alignas(16) unsigned short Als[64][264];

    const int tid  = threadIdx.x;
    const int lane = tid & 63;
    const int w    = tid >> 6;            // wave: e-strip [w*256, +256)
    const int tx   = lane & 15, tg = lane >> 4;
    const int n    = blockIdx.y;
    const int t0   = blockIdx.x << 6;

    // ---- stage A once: f32 -> bf16 hi/lo (one-time bfsplit, 16 float4/thread)
    #pragma unroll
    for (int i = 0; i < 16; ++i){
        const int idx = tid + (i << 8);
        const int row = idx >> 6, c4 = (idx & 63) << 2;
        const float4 v = *reinterpret_cast<const float4*>(
            &ic[(size_t)(t0 + row) * 1024 + (n << 8) + c4]);
        ushort4 h, l;
        bfsplit(v.x, h.x, l.x); bfsplit(v.y, h.y, l.y);
        bfsplit(v.z, h.z, l.z); bfsplit(v.w, h.w, l.w);
        *reinterpret_cast<ushort4*>(&Ahs[row][c4]) = h;
        *reinterpret_cast<ushort4*>(&Als[row][c4]) = l;
    }
    __syncthreads();

    float mn[16], mn2[16]; int mi[16];
    #pragma unroll
    for (int s = 0; s < 16; ++s){ mn[s] = 3.4e38f; mn2[s] = 3.4e38f; mi[s] = 0; }

    #pragma unroll 1
    for (int ec = 0; ec < 4; ++ec){
        f32x4 acc[4][4];
        #pragma unroll
        for (int rb = 0; rb < 4; ++rb)
            #pragma unroll
            for (int cb = 0; cb < 4; ++cb)
                acc[rb][cb] = f32x4{0.f, 0.f, 0.f, 0.f};

        #pragma unroll
        for (int ks = 0; ks < 8; ++ks){
            bf16x8 bh[4], bl[4];
            #pragma unroll
            for (int cb = 0; cb < 4; ++cb){
                const int e = (w << 8) + (ec << 6) + (cb << 4) + tx;
                const size_t g = ((size_t)((n << 10) + e) << 8) + (ks << 5) + (tg << 3);
                bh[cb] = *reinterpret_cast<const bf16x8*>(&ebh[g]);
                bl[cb] = *reinterpret_cast<const bf16x8*>(&ebl[g]);
            }
            bf16x8 ah[4], al[4];
            #pragma unroll
            for (int rb = 0; rb < 4; ++rb){
                ah[rb] = *reinterpret_cast<const bf16x8*>(&Ahs[(rb << 4) + tx][(ks << 5) + (tg << 3)]);
                al[rb] = *reinterpret_cast<const bf16x8*>(&Als[(rb << 4) + tx][(ks << 5) + (tg << 3)]);
            }
            #pragma unroll
            for (int rb = 0; rb < 4; ++rb)
                #pragma unroll
                for (int cb = 0; cb < 4; ++cb){
                    acc[rb][cb] = __builtin_amdgcn_mfma_f32_16x16x32_bf16(ah[rb], bh[cb], acc[rb][cb], 0, 0, 0);
                    acc[rb][cb] = __builtin_amdgcn_mfma_f32_16x16x32_bf16(ah[rb], bl[cb], acc[rb][cb], 0, 0, 0);
                    acc[rb][cb] = __builtin_amdgcn_mfma_f32_16x16x32_bf16(al[rb], bh[cb], acc[rb][cb], 0, 0, 0);
                }
        }
        // ---- chunk epilogue: dist = e2 - 2*dot, running min/2nd-min (e ascending)
        #pragma unroll
        for (int cb = 0; cb < 4; ++cb){
            const int e = (w << 8) + (ec << 6) + (cb << 4) + tx;
            const float ee = e2g[(n << 10) + e];
            #pragma unroll
            for (int rb = 0; rb < 4; ++rb)
                #pragma unroll
                for (int r = 0; r < 4; ++r){
                    const float v = fmaf(-2.f, acc[rb][cb][r], ee);
                    const int s = (rb << 2) + r;
                    if (v < mn[s]){ mn2[s] = mn[s]; mn[s] = v; mi[s] = e; }
                    else if (v < mn2[s]){ mn2[s] = v; }
                }
        }
    }

    // ---- reduce over the 16 tx-lanes (same rows, disjoint e)
    #pragma unroll
    for (int sft = 1; sft < 16; sft <<= 1){
        #pragma unroll
        for (int s = 0; s < 16; ++s){
            const float om  = __shfl_xor(mn[s],  sft, 64);
            const float om2 = __shfl_xor(mn2[s], sft, 64);
            const int   oi  = __shfl_xor(mi[s],  sft, 64);
            if (om < mn[s] || (om == mn[s] && oi < mi[s])){
                mn2[s] = fminf(mn[s], om2);
                mn[s] = om; mi[s] = oi;
            } else {
                mn2[s] = fminf(mn2[s], om);
            }
        }
    }
    // ---- cross-wave merge via LDS overlay (waves hold disjoint e-strips)
    __syncthreads();
    float* redMn  = reinterpret_cast<float*>(&Ahs[0][0]);
    float* redMn2 = redMn + 256;
    int*   redMi  = reinterpret_cast<int*>(redMn + 512);
    if (tx == 0){
        #pragma unroll
        for (int rb = 0; rb < 4; ++rb)
            #pragma unroll
            for (int r = 0; r < 4; ++r){
                const int row = (rb << 4) + (tg << 2) + r;
                const int s = (rb << 2) + r;
                redMn [(w << 6) + row] = mn[s];
                redMn2[(w << 6) + row] = mn2[s];
                redMi [(w << 6) + row] = mi[s];
            }
    }
    __syncthreads();
    if (tid < 64){
        const int row = tid;
        float bmn = redMn[row], bmn2 = redMn2[row];
        int   bmi = redMi[row];
        #pragma unroll
        for (int wv = 1; wv < 4; ++wv){
            const float om  = redMn [(wv << 6) + row];
            const float om2 = redMn2[(wv << 6) + row];
            const int   oi  = redMi [(wv << 6) + row];
            if (om < bmn || (om == bmn && oi < bmi)){
                bmn2 = fminf(bmn, om2);
                bmn = om; bmi = oi;
            } else {
                bmn2 = fminf(bmn2, om);
            }
        }
        const int t = t0 + row;
        idx_ws[t * 4 + n] = bmi;
        am[(size_t)t * 4 + n] = (float)bmi;
        if (bmn2 - bmn < TAU){
            const int pos = atomicAdd(cnt, 1);
            if (pos < FLAGCAP) flags[pos] = make_int2(t, n);
        }
    }
}

// ---------------------------------------------------------------- f64 re-rank of flagged rows
__global__ __launch_bounds__(256) void k_fix(
    const float* __restrict__ x,
    const float* __restrict__ w0, const float* __restrict__ w1,
    const float* __restrict__ w2, const float* __restrict__ w3,
    const float* __restrict__ b0, const float* __restrict__ b1,
    const float* __restrict__ b2, const float* __restrict__ b3,
    const float* __restrict__ embT,
    const int* __restrict__ cnt, const int2* __restrict__ flags,
    int* __restrict__ idx_ws, float* __restrict__ am)
{
    __shared__ double fl[Dm];
    __shared__ double rD[4];
    __shared__ int    rE[4];
    const int tid = threadIdx.x;
    const int total = (*cnt < FLAGCAP) ? *cnt : FLAGCAP;
    const float* wP[4] = { w0, w1, w2, w3 };
    const float* bP[4] = { b0, b1, b2, b3 };
    const int   kN[4] = { 1, 3, 5, 7 };

    for (int item = blockIdx.x; item < total; item += gridDim.x){
        const int2 f = flags[item];
        const int t = f.x, n = f.y;
        const int bb = t >> 11, s = t & (SEQ - 1);
        const int k = kN[n], pad = (k - 1) >> 1;
        // ---- f64 conv for this row, d = tid
        {
            const int d = tid;
            double acc = (double)bP[n][0];
            for (int dh = 0; dh < k; ++dh){
                const int sr = s - pad + dh;
                if ((unsigned)sr < (unsigned)SEQ){
                    const float* xr = x + (size_t)((bb << 11) + sr) * Dm;
                    const float* wr = wP[n] + dh * Dm;
                    const int lo = (d - 127 < 0) ? 0 : d - 127;        // m = input dim index
                    const int hi = (d + 129 > Dm) ? Dm : d + 129;      // j = m-d+127 in [0,255]
                    for (int m = lo; m < hi; ++m)
                        acc += (double)xr[m] * (double)wr[m - d + 127];
                }
            }
            fl[d] = (acc > 0.0) ? acc : 0.0;
        }
        __syncthreads();
        // ---- f64 distances over all 1024 embeddings (4 per thread)
        double bD = 1e300; int bE = 0;
        #pragma unroll
        for (int ee = 0; ee < 4; ++ee){
            const int e = (ee << 8) + tid;
            const float* ep = embT + ((size_t)n * NE + e) * Dm;
            double dot = 0.0, e2 = 0.0;
            for (int d = 0; d < Dm; ++d){
                const double v = (double)ep[d];
                dot += v * fl[d];
                e2  += v * v;
            }
            const double dist = e2 - 2.0 * dot;
            if (dist < bD || (dist == bD && e < bE)){ bD = dist; bE = e; }
        }
        #pragma unroll
        for (int sft = 1; sft < 64; sft <<= 1){
            const double od = __shfl_xor(bD, sft, 64);
            const int    oe = __shfl_xor(bE, sft, 64);
            if (od < bD || (od == bD && oe < bE)){ bD = od; bE = oe; }
        }
        if ((tid & 63) == 0){ rD[tid >> 6] = bD; rE[tid >> 6] = bE; }
        __syncthreads();
        if (tid == 0){
            #pragma unroll
            for (int wv = 1; wv < 4; ++wv)
                if (rD[wv] < rD[0] || (rD[wv] == rD[0] && rE[wv] < rE[0])){
                    rD[0] = rD[wv]; rE[0] = rE[wv];
                }
            idx_ws[t * 4 + n] = rE[0];
            am[(size_t)t * 4 + n] = (float)rE[0];
        }
        __syncthreads();
    }
}

// ---------------------------------------------------------------- gather + gate + z_q
__global__ __launch_bounds__(256) void k_final(
    const int* __restrict__ idx_ws, const float* __restrict__ embT,
    const float* __restrict__ gw, const float* __restrict__ gb,
    float* __restrict__ qc, float* __restrict__ zq)
{
    __shared__ float gws[4][Dm];
    const int tid = threadIdx.x;
    for (int i = tid; i < 4 * Dm; i += 256) gws[i >> 8][i & 255] = gw[i];
    __syncthreads();
    const int t = (blockIdx.x << 2) + (tid >> 6);
    const int lane = tid & 63, d0 = lane << 2;

    float q[4][4];
    #pragma unroll
    for (int n = 0; n < 4; ++n){
        const int e = idx_ws[t * 4 + n];
        const float4 v = *reinterpret_cast<const float4*>(
            &embT[((size_t)n * NE + e) * Dm + d0]);
        q[n][0] = v.x; q[n][1] = v.y; q[n][2] = v.z; q[n][3] = v.w;
        *reinterpret_cast<float4*>(&qc[(size_t)t * 1024 + n * Dm + d0]) = v;
    }
    float part[4];
    #pragma unroll
    for (int n = 0; n < 4; ++n){
        part[n] = q[0][0] * gws[n][d0]     + q[0][1] * gws[n][d0 + 1]
                + q[0][2] * gws[n][d0 + 2] + q[0][3] * gws[n][d0 + 3];
    }
    #pragma unroll
    for (int s = 1; s < 64; s <<= 1){
        #pragma unroll
        for (int n = 0; n < 4; ++n) part[n] += __shfl_xor(part[n], s, 64);
    }
    float lg[4];
    #pragma unroll
    for (int n = 0; n < 4; ++n) lg[n] = part[n] + gb[n];
    const float mx = fmaxf(fmaxf(lg[0], lg[1]), fmaxf(lg[2], lg[3]));
    float ex[4], ssum = 0.f;
    #pragma unroll
    for (int n = 0; n < 4; ++n){ ex[n] = expf(lg[n] - mx); ssum += ex[n]; }
    const float inv = 1.f / ssum;
    float z[4];
    #pragma unroll
    for (int dd = 0; dd < 4; ++dd)
        z[dd] = (ex[0] * q[0][dd] + ex[1] * q[1][dd] + ex[2] * q[2][dd] + ex[3] * q[3][dd]) * inv;
    *reinterpret_cast<float4*>(&zq[(size_t)t * Dm + d0]) =
        make_float4(z[0], z[1], z[2], z[3]);
}

// ---------------------------------------------------------------- launch
extern "C" void kernel_launch(void* const* d_in, const int* in_sizes, int n_in,
                              void* d_out, int out_size, void* d_ws, size_t ws_size,
                              hipStream_t stream)
{
    const float* x   = (const float*)d_in[0];
    const float* w0  = (const float*)d_in[1];
    const float* b0  = (const float*)d_in[2];
    const float* w1  = (const float*)d_in[3];
    const float* b1  = (const float*)d_in[4];
    const float* w2  = (const float*)d_in[5];
    const float* b2  = (const float*)d_in[6];
    const float* w3  = (const float*)d_in[7];
    const float* b3  = (const float*)d_in[8];
    const float* emb = (const float*)d_in[9];
    const float* gw  = (const float*)d_in[10];
    const float* gb  = (const float*)d_in[11];

    float* out = (float*)d_out;
    float* zq = out;                    //  4,194,304  (T x 256)
    float* am = out + 4194304;          //     65,536  (T x 4)
    float* ic = out + 4259840;          // 16,777,216  (T x 1024)
    float* qc = out + 21037056;         // 16,777,216  (T x 1024)

    float* ws    = (float*)d_ws;
    float* embT  = ws;                                  // [4][1024][256] f32
    float* e2    = ws + 1048576;                        // [4][1024]      f32
    int*   idxs  = (int*)(ws + 1052672);                // [16384][4]     i32
    int*   cnt   = (int*)(ws + 1118208);                // 1 i32
    int2*  flags = (int2*)(ws + 1118212);               // FLAGCAP int2
    unsigned short* ebh = (unsigned short*)(ws + 1380360);  // [4][1024][256] bf16 hi
    unsigned short* ebl = (unsigned short*)(ws + 1904648);  // [4][1024][256] bf16 lo

    hipLaunchKernelGGL(k_transpose, dim3(32, 8, 4), dim3(32, 8), 0, stream, emb, embT);
    hipLaunchKernelGGL(k_e2,        dim3(4, 4),     dim3(256),   0, stream, emb, e2, cnt);
    hipLaunchKernelGGL(k_cvt,       dim3(1024),     dim3(256),   0, stream, embT, ebh, ebl);
    hipLaunchKernelGGL(k_conv,      dim3(4096),     dim3(256),   0, stream,
                       x, w0, w1, w2, w3, b0, b1, b2, b3, ic);
    hipLaunchKernelGGL(k_vq,        dim3(256, 4),   dim3(256),   0, stream,
                       ic, ebh, ebl, e2, idxs, am, cnt, flags);
    hipLaunchKernelGGL(k_fix,       dim3(512),      dim3(256),   0, stream,
                       x, w0, w1, w2, w3, b0, b1, b2, b3, embT, cnt, flags, idxs, am);
    hipLaunchKernelGGL(k_final,     dim3(4096),     dim3(256),   0, stream,
                       idxs, embT, gw, gb, qc, zq);
}

// Round 8
// 735.243 us; speedup vs baseline: 2.0921x; 1.2083x over previous
//
#include <hip/hip_runtime.h>
#include <hip/hip_bf16.h>

#define SEQ   2048
#define Dm    256
#define NE    1024
#define TT    16384   // B*S = 8*2048
#define TAU   0.05f   // near-tie gap threshold for f64 re-rank
#define FLAGCAP 131072

typedef __attribute__((ext_vector_type(8))) short          bf16x8;
typedef __attribute__((ext_vector_type(4))) float          f32x4;
typedef __attribute__((ext_vector_type(8))) unsigned short us8;

__device__ __forceinline__ void bfsplit(float x, unsigned short& h, unsigned short& l){
    __hip_bfloat16 bh = __float2bfloat16(x);
    h = *reinterpret_cast<unsigned short*>(&bh);
    union { unsigned u; float f; } c; c.u = (unsigned)h << 16;
    __hip_bfloat16 bl = __float2bfloat16(x - c.f);
    l = *reinterpret_cast<unsigned short*>(&bl);
}

// ---------------------------------------------------------------- transpose
__global__ void k_transpose(const float* __restrict__ emb, float* __restrict__ embT){
    __shared__ float tile[32][33];
    const int n  = blockIdx.z;
    const int e0 = blockIdx.x << 5, d0 = blockIdx.y << 5;
    const int tx = threadIdx.x, ty = threadIdx.y;
    const float* src = emb + (size_t)n * Dm * NE;
    float* dst = embT + (size_t)n * NE * Dm;
    #pragma unroll
    for (int i = ty; i < 32; i += 8)
        tile[i][tx] = src[(size_t)(d0 + i) * NE + e0 + tx];
    __syncthreads();
    #pragma unroll
    for (int i = ty; i < 32; i += 8)
        dst[(size_t)(e0 + i) * Dm + d0 + tx] = tile[tx][i];
}

// ---------------------------------------------------------------- e2 norms (+ zero flag counter)
__global__ void k_e2(const float* __restrict__ emb, float* __restrict__ e2,
                     int* __restrict__ cnt){
    if (blockIdx.x == 0 && blockIdx.y == 0 && threadIdx.x == 0) *cnt = 0;
    const int n = blockIdx.y;
    const int e = (blockIdx.x << 8) + threadIdx.x;
    const float* p = emb + (size_t)n * Dm * NE + e;
    float s = 0.f;
    #pragma unroll 8
    for (int d = 0; d < Dm; ++d){ float v = p[(size_t)d * NE]; s = fmaf(v, v, s); }
    e2[n * NE + e] = s;
}

// ---------------------------------------------------------------- split embT into bf16 hi/lo
__global__ __launch_bounds__(256) void k_cvt(const float* __restrict__ embT,
                                             unsigned short* __restrict__ eh,
                                             unsigned short* __restrict__ el){
    const int i = ((blockIdx.x << 8) + threadIdx.x) << 2;
    const float4 v = *reinterpret_cast<const float4*>(&embT[i]);
    ushort4 h, l;
    bfsplit(v.x, h.x, l.x); bfsplit(v.y, h.y, l.y);
    bfsplit(v.z, h.z, l.z); bfsplit(v.w, h.w, l.w);
    *reinterpret_cast<ushort4*>(&eh[i]) = h;
    *reinterpret_cast<ushort4*>(&el[i]) = l;
}

// ---------------------------------------------------------------- prep banded conv weights
// Bt[n][dh][d][m] = w_n[dh][m-d+127] (0 outside band), split bf16 hi/lo.
__global__ __launch_bounds__(256) void k_prep(
    const float* __restrict__ w0, const float* __restrict__ w1,
    const float* __restrict__ w2, const float* __restrict__ w3,
    unsigned short* __restrict__ bth, unsigned short* __restrict__ btl)
{
    const int dh = blockIdx.x;            // 0..6
    const int n  = blockIdx.y;            // 0..3
    const int kk = 2 * n + 1;
    if (dh >= kk) return;
    const float* wr[4] = { w0, w1, w2, w3 };
    const float* wp = wr[n] + dh * Dm;
    const int d = threadIdx.x;
    const size_t base = ((size_t)((n * 7 + dh) * 256 + d)) << 8;
    for (int mc = 0; mc < 256; mc += 4){
        ushort4 h, l;
        #pragma unroll
        for (int q = 0; q < 4; ++q){
            const int j = mc + q - d + 127;
            const float v = ((unsigned)j < 256u) ? wp[j] : 0.f;
            unsigned short hh, ll;
            bfsplit(v, hh, ll);
            (&h.x)[q] = hh; (&l.x)[q] = ll;
        }
        *reinterpret_cast<ushort4*>(&bth[base + mc]) = h;
        *reinterpret_cast<ushort4*>(&btl[base + mc]) = l;
    }
}

// ---------------------------------------------------------------- conv via split-bf16 MFMA
__global__ __launch_bounds__(256, 2) void k_conv(
    const float* __restrict__ x,
    const unsigned short* __restrict__ bth, const unsigned short* __restrict__ btl,
    const float* __restrict__ b0, const float* __restrict__ b1,
    const float* __restrict__ b2, const float* __restrict__ b3,
    float* __restrict__ ic)
{
    __shared__ alignas(16) unsigned short Ahs[70][264];
    __shared__ alignas(16) unsigned short Als[70][264];

    const int tid  = threadIdx.x;
    const int lane = tid & 63;
    const int w    = tid >> 6;
    const int tx   = lane & 15, tg = lane >> 4;
    const int bx   = blockIdx.x;
    const int n    = bx & 3;
    const int t0   = (bx >> 2) << 6;
    const int bb   = t0 >> 11, s0 = t0 & (SEQ - 1);
    const int kk   = 2 * n + 1, pad = n;
    const int nrows = 64 + 2 * pad;

    // ---- stage A once: rows r <-> s = s0 - pad + r, zero outside sequence
    for (int idx = tid; idx < (nrows << 6); idx += 256){
        const int r = idx >> 6, c4 = (idx & 63) << 2;
        const int s = s0 - pad + r;
        float4 v = make_float4(0.f, 0.f, 0.f, 0.f);
        if ((unsigned)s < (unsigned)SEQ)
            v = *reinterpret_cast<const float4*>(&x[(size_t)((bb << 11) + s) * Dm + c4]);
        ushort4 h, l;
        bfsplit(v.x, h.x, l.x); bfsplit(v.y, h.y, l.y);
        bfsplit(v.z, h.z, l.z); bfsplit(v.w, h.w, l.w);
        *reinterpret_cast<ushort4*>(&Ahs[r][c4]) = h;
        *reinterpret_cast<ushort4*>(&Als[r][c4]) = l;
    }
    __syncthreads();

    f32x4 acc[4][4];
    #pragma unroll
    for (int rb = 0; rb < 4; ++rb)
        #pragma unroll
        for (int cb = 0; cb < 4; ++cb)
            acc[rb][cb] = f32x4{0.f, 0.f, 0.f, 0.f};

    #pragma unroll 1
    for (int dh = 0; dh < kk; ++dh){
        #pragma unroll
        for (int ks = 0; ks < 8; ++ks){
            const int m0 = ks << 5;
            bf16x8 ah[4], al[4];
            #pragma unroll
            for (int rb = 0; rb < 4; ++rb){
                const int row = (rb << 4) + tx + dh;
                ah[rb] = *reinterpret_cast<const bf16x8*>(&Ahs[row][m0 + (tg << 3)]);
                al[rb] = *reinterpret_cast<const bf16x8*>(&Als[row][m0 + (tg << 3)]);
            }
            #pragma unroll
            for (int cb = 0; cb < 4; ++cb){
                const int d0 = (w << 6) + (cb << 4);
                if (m0 <= d0 + 143 && m0 >= d0 - 158){   // band-nonzero (wave-uniform)
                    const size_t g = ((size_t)((n * 7 + dh) * 256 + d0 + tx) << 8) + m0 + (tg << 3);
                    const bf16x8 bh = *reinterpret_cast<const bf16x8*>(&bth[g]);
                    const bf16x8 bl = *reinterpret_cast<const bf16x8*>(&btl[g]);
                    #pragma unroll
                    for (int rb = 0; rb < 4; ++rb){
                        acc[rb][cb] = __builtin_amdgcn_mfma_f32_16x16x32_bf16(ah[rb], bh, acc[rb][cb], 0, 0, 0);
                        acc[rb][cb] = __builtin_amdgcn_mfma_f32_16x16x32_bf16(ah[rb], bl, acc[rb][cb], 0, 0, 0);
                        acc[rb][cb] = __builtin_amdgcn_mfma_f32_16x16x32_bf16(al[rb], bh, acc[rb][cb], 0, 0, 0);
                    }
                }
            }
        }
    }

    // ---- epilogue: bias + ReLU + store
    const float* bP[4] = { b0, b1, b2, b3 };
    const float bias = bP[n][0];
    #pragma unroll
    for (int rb = 0; rb < 4; ++rb)
        #pragma unroll
        for (int cb = 0; cb < 4; ++cb)
            #pragma unroll
            for (int r = 0; r < 4; ++r){
                const int trow = (rb << 4) + (tg << 2) + r;
                const int d    = (w << 6) + (cb << 4) + tx;
                const float v  = fmaxf(acc[rb][cb][r] + bias, 0.f);
                ic[(size_t)(t0 + trow) * 1024 + (n << 8) + d] = v;
            }
}

// ---------------------------------------------------------------- VQ argmin v3
__global__ __launch_bounds__(256, 2) void k_vq(
    const float* __restrict__ ic,
    const unsigned short* __restrict__ ebh, const unsigned short* __restrict__ ebl,
    const float* __restrict__ e2g, int* __restrict__ idx_ws, float* __restrict__ am,
    int* __restrict__ cnt, int2* __restrict__ flags)
{
    __shared__ alignas(16) unsigned short Ahs[64][264];
    __shared__ alignas(16) unsigned short Als[64][264];

    const int tid  = threadIdx.x;
    const int lane = tid & 63;
    const int w    = tid >> 6;
    const int tx   = lane & 15, tg = lane >> 4;
    const int n    = blockIdx.y;
    const int t0   = blockIdx.x << 6;

    #pragma unroll
    for (int i = 0; i < 16; ++i){
        const int idx = tid + (i << 8);
        const int row = idx >> 6, c4 = (idx & 63) << 2;
        const float4 v = *reinterpret_cast<const float4*>(
            &ic[(size_t)(t0 + row) * 1024 + (n << 8) + c4]);
        ushort4 h, l;
        bfsplit(v.x, h.x, l.x); bfsplit(v.y, h.y, l.y);
        bfsplit(v.z, h.z, l.z); bfsplit(v.w, h.w, l.w);
        *reinterpret_cast<ushort4*>(&Ahs[row][c4]) = h;
        *reinterpret_cast<ushort4*>(&Als[row][c4]) = l;
    }
    __syncthreads();

    float mn[16], mn2[16]; int mi[16];
    #pragma unroll
    for (int s = 0; s < 16; ++s){ mn[s] = 3.4e38f; mn2[s] = 3.4e38f; mi[s] = 0; }

    #pragma unroll 1
    for (int ec = 0; ec < 4; ++ec){
        f32x4 acc[4][4];
        #pragma unroll
        for (int rb = 0; rb < 4; ++rb)
            #pragma unroll
            for (int cb = 0; cb < 4; ++cb)
                acc[rb][cb] = f32x4{0.f, 0.f, 0.f, 0.f};

        #pragma unroll
        for (int ks = 0; ks < 8; ++ks){
            bf16x8 bh[4], bl[4];
            #pragma unroll
            for (int cb = 0; cb < 4; ++cb){
                const int e = (w << 8) + (ec << 6) + (cb << 4) + tx;
                const size_t g = ((size_t)((n << 10) + e) << 8) + (ks << 5) + (tg << 3);
                bh[cb] = *reinterpret_cast<const bf16x8*>(&ebh[g]);
                bl[cb] = *reinterpret_cast<const bf16x8*>(&ebl[g]);
            }
            bf16x8 ah[4], al[4];
            #pragma unroll
            for (int rb = 0; rb < 4; ++rb){
                ah[rb] = *reinterpret_cast<const bf16x8*>(&Ahs[(rb << 4) + tx][(ks << 5) + (tg << 3)]);
                al[rb] = *reinterpret_cast<const bf16x8*>(&Als[(rb << 4) + tx][(ks << 5) + (tg << 3)]);
            }
            #pragma unroll
            for (int rb = 0; rb < 4; ++rb)
                #pragma unroll
                for (int cb = 0; cb < 4; ++cb){
                    acc[rb][cb] = __builtin_amdgcn_mfma_f32_16x16x32_bf16(ah[rb], bh[cb], acc[rb][cb], 0, 0, 0);
                    acc[rb][cb] = __builtin_amdgcn_mfma_f32_16x16x32_bf16(ah[rb], bl[cb], acc[rb][cb], 0, 0, 0);
                    acc[rb][cb] = __builtin_amdgcn_mfma_f32_16x16x32_bf16(al[rb], bh[cb], acc[rb][cb], 0, 0, 0);
                }
        }
        #pragma unroll
        for (int cb = 0; cb < 4; ++cb){
            const int e = (w << 8) + (ec << 6) + (cb << 4) + tx;
            const float ee = e2g[(n << 10) + e];
            #pragma unroll
            for (int rb = 0; rb < 4; ++rb)
                #pragma unroll
                for (int r = 0; r < 4; ++r){
                    const float v = fmaf(-2.f, acc[rb][cb][r], ee);
                    const int s = (rb << 2) + r;
                    if (v < mn[s]){ mn2[s] = mn[s]; mn[s] = v; mi[s] = e; }
                    else if (v < mn2[s]){ mn2[s] = v; }
                }
        }
    }

    #pragma unroll
    for (int sft = 1; sft < 16; sft <<= 1){
        #pragma unroll
        for (int s = 0; s < 16; ++s){
            const float om  = __shfl_xor(mn[s],  sft, 64);
            const float om2 = __shfl_xor(mn2[s], sft, 64);
            const int   oi  = __shfl_xor(mi[s],  sft, 64);
            if (om < mn[s] || (om == mn[s] && oi < mi[s])){
                mn2[s] = fminf(mn[s], om2);
                mn[s] = om; mi[s] = oi;
            } else {
                mn2[s] = fminf(mn2[s], om);
            }
        }
    }
    __syncthreads();
    float* redMn  = reinterpret_cast<float*>(&Ahs[0][0]);
    float* redMn2 = redMn + 256;
    int*   redMi  = reinterpret_cast<int*>(redMn + 512);
    if (tx == 0){
        #pragma unroll
        for (int rb = 0; rb < 4; ++rb)
            #pragma unroll
            for (int r = 0; r < 4; ++r){
                const int row = (rb << 4) + (tg << 2) + r;
                const int s = (rb << 2) + r;
                redMn [(w << 6) + row] = mn[s];
                redMn2[(w << 6) + row] = mn2[s];
                redMi [(w << 6) + row] = mi[s];
            }
    }
    __syncthreads();
    if (tid < 64){
        const int row = tid;
        float bmn = redMn[row], bmn2 = redMn2[row];
        int   bmi = redMi[row];
        #pragma unroll
        for (int wv = 1; wv < 4; ++wv){
            const float om  = redMn [(wv << 6) + row];
            const float om2 = redMn2[(wv << 6) + row];
            const int   oi  = redMi [(wv << 6) + row];
            if (om < bmn || (om == bmn && oi < bmi)){
                bmn2 = fminf(bmn, om2);
                bmn = om; bmi = oi;
            } else {
                bmn2 = fminf(bmn2, om);
            }
        }
        const int t = t0 + row;
        idx_ws[t * 4 + n] = bmi;
        am[(size_t)t * 4 + n] = (float)bmi;
        if (bmn2 - bmn < TAU){
            const int pos = atomicAdd(cnt, 1);
            if (pos < FLAGCAP) flags[pos] = make_int2(t, n);
        }
    }
}

// ---------------------------------------------------------------- f64 re-rank of flagged rows
__global__ __launch_bounds__(256) void k_fix(
    const float* __restrict__ x,
    const float* __restrict__ w0, const float* __restrict__ w1,
    const float* __restrict__ w2, const float* __restrict__ w3,
    const float* __restrict__ b0, const float* __restrict__ b1,
    const float* __restrict__ b2, const float* __restrict__ b3,
    const float* __restrict__ embT,
    const int* __restrict__ cnt, const int2* __restrict__ flags,
    int* __restrict__ idx_ws, float* __restrict__ am)
{
    __shared__ double fl[Dm];
    __shared__ double rD[4];
    __shared__ int    rE[4];
    const int tid = threadIdx.x;
    const int total = (*cnt < FLAGCAP) ? *cnt : FLAGCAP;
    const float* wP[4] = { w0, w1, w2, w3 };
    const float* bP[4] = { b0, b1, b2, b3 };
    const int   kN[4] = { 1, 3, 5, 7 };

    for (int item = blockIdx.x; item < total; item += gridDim.x){
        const int2 f = flags[item];
        const int t = f.x, n = f.y;
        const int bb = t >> 11, s = t & (SEQ - 1);
        const int k = kN[n], pad = (k - 1) >> 1;
        {
            const int d = tid;
            double acc = (double)bP[n][0];
            for (int dh = 0; dh < k; ++dh){
                const int sr = s - pad + dh;
                if ((unsigned)sr < (unsigned)SEQ){
                    const float* xr = x + (size_t)((bb << 11) + sr) * Dm;
                    const float* wr = wP[n] + dh * Dm;
                    const int lo = (d - 127 < 0) ? 0 : d - 127;
                    const int hi = (d + 129 > Dm) ? Dm : d + 129;
                    for (int m = lo; m < hi; ++m)
                        acc += (double)xr[m] * (double)wr[m - d + 127];
                }
            }
            fl[d] = (acc > 0.0) ? acc : 0.0;
        }
        __syncthreads();
        double bD = 1e300; int bE = 0;
        #pragma unroll
        for (int ee = 0; ee < 4; ++ee){
            const int e = (ee << 8) + tid;
            const float* ep = embT + ((size_t)n * NE + e) * Dm;
            double dot = 0.0, e2 = 0.0;
            for (int d = 0; d < Dm; ++d){
                const double v = (double)ep[d];
                dot += v * fl[d];
                e2  += v * v;
            }
            const double dist = e2 - 2.0 * dot;
            if (dist < bD || (dist == bD && e < bE)){ bD = dist; bE = e; }
        }
        #pragma unroll
        for (int sft = 1; sft < 64; sft <<= 1){
            const double od = __shfl_xor(bD, sft, 64);
            const int    oe = __shfl_xor(bE, sft, 64);
            if (od < bD || (od == bD && oe < bE)){ bD = od; bE = oe; }
        }
        if ((tid & 63) == 0){ rD[tid >> 6] = bD; rE[tid >> 6] = bE; }
        __syncthreads();
        if (tid == 0){
            #pragma unroll
            for (int wv = 1; wv < 4; ++wv)
                if (rD[wv] < rD[0] || (rD[wv] == rD[0] && rE[wv] < rE[0])){
                    rD[0] = rD[wv]; rE[0] = rE[wv];
                }
            idx_ws[t * 4 + n] = rE[0];
            am[(size_t)t * 4 + n] = (float)rE[0];
        }
        __syncthreads();
    }
}

// ---------------------------------------------------------------- gather + gate + z_q
__global__ __launch_bounds__(256) void k_final(
    const int* __restrict__ idx_ws, const float* __restrict__ embT,
    const float* __restrict__ gw, const float* __restrict__ gb,
    float* __restrict__ qc, float* __restrict__ zq)
{
    __shared__ float gws[4][Dm];
    const int tid = threadIdx.x;
    for (int i = tid; i < 4 * Dm; i += 256) gws[i >> 8][i & 255] = gw[i];
    __syncthreads();
    const int t = (blockIdx.x << 2) + (tid >> 6);
    const int lane = tid & 63, d0 = lane << 2;

    float q[4][4];
    #pragma unroll
    for (int n = 0; n < 4; ++n){
        const int e = idx_ws[t * 4 + n];
        const float4 v = *reinterpret_cast<const float4*>(
            &embT[((size_t)n * NE + e) * Dm + d0]);
        q[n][0] = v.x; q[n][1] = v.y; q[n][2] = v.z; q[n][3] = v.w;
        *reinterpret_cast<float4*>(&qc[(size_t)t * 1024 + n * Dm + d0]) = v;
    }
    float part[4];
    #pragma unroll
    for (int n = 0; n < 4; ++n){
        part[n] = q[0][0] * gws[n][d0]     + q[0][1] * gws[n][d0 + 1]
                + q[0][2] * gws[n][d0 + 2] + q[0][3] * gws[n][d0 + 3];
    }
    #pragma unroll
    for (int s = 1; s < 64; s <<= 1){
        #pragma unroll
        for (int n = 0; n < 4; ++n) part[n] += __shfl_xor(part[n], s, 64);
    }
    float lg[4];
    #pragma unroll
    for (int n = 0; n < 4; ++n) lg[n] = part[n] + gb[n];
    const float mx = fmaxf(fmaxf(lg[0], lg[1]), fmaxf(lg[2], lg[3]));
    float ex[4], ssum = 0.f;
    #pragma unroll
    for (int n = 0; n < 4; ++n){ ex[n] = expf(lg[n] - mx); ssum += ex[n]; }
    const float inv = 1.f / ssum;
    float z[4];
    #pragma unroll
    for (int dd = 0; dd < 4; ++dd)
        z[dd] = (ex[0] * q[0][dd] + ex[1] * q[1][dd] + ex[2] * q[2][dd] + ex[3] * q[3][dd]) * inv;
    *reinterpret_cast<float4*>(&zq[(size_t)t * Dm + d0]) =
        make_float4(z[0], z[1], z[2], z[3]);
}

// ---------------------------------------------------------------- launch
extern "C" void kernel_launch(void* const* d_in, const int* in_sizes, int n_in,
                              void* d_out, int out_size, void* d_ws, size_t ws_size,
                              hipStream_t stream)
{
    const float* x   = (const float*)d_in[0];
    const float* w0  = (const float*)d_in[1];
    const float* b0  = (const float*)d_in[2];
    const float* w1  = (const float*)d_in[3];
    const float* b1  = (const float*)d_in[4];
    const float* w2  = (const float*)d_in[5];
    const float* b2  = (const float*)d_in[6];
    const float* w3  = (const float*)d_in[7];
    const float* b3  = (const float*)d_in[8];
    const float* emb = (const float*)d_in[9];
    const float* gw  = (const float*)d_in[10];
    const float* gb  = (const float*)d_in[11];

    float* out = (float*)d_out;
    float* zq = out;                    //  4,194,304  (T x 256)
    float* am = out + 4194304;          //     65,536  (T x 4)
    float* ic = out + 4259840;          // 16,777,216  (T x 1024)
    float* qc = out + 21037056;         // 16,777,216  (T x 1024)

    float* ws    = (float*)d_ws;
    float* embT  = ws;                                      // [4][1024][256] f32
    float* e2    = ws + 1048576;                            // [4][1024]      f32
    int*   idxs  = (int*)(ws + 1052672);                    // [16384][4]     i32
    int*   cnt   = (int*)(ws + 1118208);                    // 1 i32
    int2*  flags = (int2*)(ws + 1118212);                   // FLAGCAP int2 -> ends 1380356
    unsigned short* ebh = (unsigned short*)(ws + 1380360);  // [4][1024][256] bf16 hi (524288 f)
    unsigned short* ebl = (unsigned short*)(ws + 1904648);  // [4][1024][256] bf16 lo (524288 f)
    unsigned short* bth = (unsigned short*)(ws + 2428936);  // [4][7][256][256] bf16 hi (917504 f)
    unsigned short* btl = (unsigned short*)(ws + 3346440);  // [4][7][256][256] bf16 lo (917504 f)

    hipLaunchKernelGGL(k_transpose, dim3(32, 8, 4), dim3(32, 8), 0, stream, emb, embT);
    hipLaunchKernelGGL(k_e2,        dim3(4, 4),     dim3(256),   0, stream, emb, e2, cnt);
    hipLaunchKernelGGL(k_cvt,       dim3(1024),     dim3(256),   0, stream, embT, ebh, ebl);
    hipLaunchKernelGGL(k_prep,      dim3(7, 4),     dim3(256),   0, stream,
                       w0, w1, w2, w3, bth, btl);
    hipLaunchKernelGGL(k_conv,      dim3(1024),     dim3(256),   0, stream,
                       x, bth, btl, b0, b1, b2, b3, ic);
    hipLaunchKernelGGL(k_vq,        dim3(256, 4),   dim3(256),   0, stream,
                       ic, ebh, ebl, e2, idxs, am, cnt, flags);
    hipLaunchKernelGGL(k_fix,       dim3(512),      dim3(256),   0, stream,
                       x, w0, w1, w2, w3, b0, b1, b2, b3, embT, cnt, flags, idxs, am);
    hipLaunchKernelGGL(k_final,     dim3(4096),     dim3(256),   0, stream,
                       idxs, embT, gw, gb, qc, zq);
}